// Round 5
// baseline (926.856 us; speedup 1.0000x reference)
//
#include <hip/hip_runtime.h>
#include <hip/hip_bf16.h>
#include <cstdint>
#include <cstddef>

// tanh_max attention, B=4 H=12 S=2048 D=32, fp32 in/out. attn_mask is a
// faithful no-op in the reference -> never read.
//
// R5: 32 queries per wave (two 16x16 A-frags) x 1024 keys.
//   R3 == R4 showed the kernel is throughput-bound on a shared stream, not
//   latency-bound; the scalable term is K/V frag traffic per query. Doubling
//   queries/wave halves L2/L1 bytes (1.57 GB -> 786 MB) and P-transpose LDS
//   traffic per element, at constant trans/VALU per element (those are at
//   their floor).
//   - grid 1536: block = 2 q-groups(32q) x 2 key-halves, 4 waves.
//   - P round trip in-iteration (single buffer; R4's P-pipeline was neutral).
//   - K-frags register-prefetched one chunk ahead; V loaded early in-iter.
//   - launch_bounds(256,4): ~100 VGPR state, avoid forced spills.

#define SLEN 2048
#define DK   32
#define NBH  48
#define PROW 40   // P row stride in bf16 (80 B, 16B-aligned)
#define NCH  32   // 32-key chunks per wave (1024 keys)

typedef __attribute__((ext_vector_type(8))) short bf16x8;
typedef __attribute__((ext_vector_type(4))) float f32x4;

__device__ __forceinline__ unsigned pk2(float a, float b) {
    __hip_bfloat162 h = __float22bfloat162_rn(make_float2(a, b));
    union { __hip_bfloat162 h2; unsigned u; } cv; cv.h2 = h; return cv.u;
}

// ---- fused prep: K -> Kbf (frag order, even/odd interleave);
//                  V -> VTf (V^T frag order) --------------------------------
__global__ __launch_bounds__(256)
void prep_kv(const float* __restrict__ K, const float* __restrict__ V,
             unsigned short* __restrict__ Kbf, unsigned short* __restrict__ VTf) {
    if (blockIdx.x < NBH * 32) {
        const int b  = blockIdx.x;
        const int bh = b >> 5, kg = b & 31;
        const int tl = threadIdx.x >> 6, l = threadIdx.x & 63;
        const int t  = kg * 4 + tl;
        const int c  = t >> 1, tb = t & 1;
        const int key = c * 32 + 2 * (l & 15) + tb;
        const float* src = K + ((size_t)bh * SLEN + key) * DK + (l >> 4) * 8;
        float4 a = *(const float4*)src;
        float4 b4 = *(const float4*)(src + 4);
        union { uint4 q; unsigned u[4]; } o;
        o.u[0] = pk2(a.x, a.y);  o.u[1] = pk2(a.z, a.w);
        o.u[2] = pk2(b4.x, b4.y); o.u[3] = pk2(b4.z, b4.w);
        *(uint4*)(Kbf + (((size_t)bh * 128 + t) * 64 + l) * 8) = o.q;
    } else {
        __shared__ float tile[32][33];
        const int b  = blockIdx.x - NBH * 32;
        const int bh = b >> 6, c = b & 63;
        const int t  = threadIdx.x;
        {
            const int row = t >> 3, c4 = (t & 7) * 4;
            float4 v4 = *(const float4*)(V + ((size_t)bh * SLEN + c * 32 + row) * DK + c4);
            tile[row][c4 + 0] = v4.x; tile[row][c4 + 1] = v4.y;
            tile[row][c4 + 2] = v4.z; tile[row][c4 + 3] = v4.w;
        }
        __syncthreads();
        const int h = t >> 7, l = (t >> 1) & 63, jh = t & 1;
        const int col = h * 16 + (l & 15);
        const int r0  = (l >> 4) * 8 + jh * 4;
        uint2 u;
        u.x = pk2(tile[r0 + 0][col], tile[r0 + 1][col]);
        u.y = pk2(tile[r0 + 2][col], tile[r0 + 3][col]);
        *(uint2*)(VTf + ((((size_t)bh * 64 + c) * 2 + h) * 64 + l) * 8 + jh * 4) = u;
    }
}

// ---- main: MFMA attention, 32 q per wave -----------------------------------
__global__ __launch_bounds__(256, 4)
void attn_mfma(const float* __restrict__ Q, const unsigned short* __restrict__ Kbf,
               const unsigned short* __restrict__ VTf, float* __restrict__ Out) {
    __shared__ __align__(16) unsigned short Pbuf[4][32 * PROW];  // 10240 B
    __shared__ __align__(16) float Red[2][64][24];               // 12288 B

    const int tid  = threadIdx.x;
    const int lane = tid & 63;
    const int wv   = tid >> 6;
    const int quad = lane >> 4;
    const int l16  = lane & 15;
    const int qi   = wv >> 1;          // q-group within block
    const int kh   = wv & 1;           // key half

    // XCD-aware head clustering: 6 heads per XCD.
    const int b   = blockIdx.x;        // grid = 1536
    const int xcd = b & 7;
    const int i   = b >> 3;            // 0..191
    const int bh  = xcd * 6 + (i % 6);
    const int j   = i / 6;             // 0..31
    const int qbase = (j * 2 + qi) * 32;

    // Q a-frags (two 16-query tiles), scaled by (1/sqrt(32))*log2(e)
    const float sc = 0.17677669529663687f * 1.4426950408889634f;
    union { bf16x8 v; unsigned u[4]; } aQ0, aQ1;
    {
        const float* qp0 = Q + ((size_t)bh * SLEN + qbase + l16) * DK + quad * 8;
        float4 qa = *(const float4*)qp0;
        float4 qb = *(const float4*)(qp0 + 4);
        aQ0.u[0] = pk2(qa.x * sc, qa.y * sc); aQ0.u[1] = pk2(qa.z * sc, qa.w * sc);
        aQ0.u[2] = pk2(qb.x * sc, qb.y * sc); aQ0.u[3] = pk2(qb.z * sc, qb.w * sc);
        const float* qp1 = qp0 + 16 * DK;
        float4 qc = *(const float4*)qp1;
        float4 qd = *(const float4*)(qp1 + 4);
        aQ1.u[0] = pk2(qc.x * sc, qc.y * sc); aQ1.u[1] = pk2(qc.z * sc, qc.w * sc);
        aQ1.u[2] = pk2(qd.x * sc, qd.y * sc); aQ1.u[3] = pk2(qd.z * sc, qd.w * sc);
    }

    // frag streams for this wave's key half (chunk c: tiles at c*128 + {0,64})
    const bf16x8* kf = (const bf16x8*)Kbf + ((size_t)bh * 128 + kh * 64) * 64 + lane;
    const bf16x8* vf = (const bf16x8*)VTf + ((size_t)bh * 128 + kh * 64) * 64 + lane;

    f32x4 o00 = {0,0,0,0}, o01 = {0,0,0,0};   // q-tile0: d 0..15 / 16..31
    f32x4 o10 = {0,0,0,0}, o11 = {0,0,0,0};   // q-tile1
    f32x4 den0 = {0,0,0,0}, den1 = {0,0,0,0};
    const f32x4 zero = {0,0,0,0};

    unsigned short* pb  = &Pbuf[wv][0];
    unsigned*       pbw = (unsigned*)pb;

    bf16x8 k0 = kf[0], k1 = kf[64];

    for (int c = 0; c < NCH; ++c) {
        // scores for both q-tiles (K-frags loaded one iteration ago)
        f32x4 s00 = __builtin_amdgcn_mfma_f32_16x16x32_bf16(aQ0.v, k0, zero, 0, 0, 0);
        f32x4 s01 = __builtin_amdgcn_mfma_f32_16x16x32_bf16(aQ0.v, k1, zero, 0, 0, 0);
        f32x4 s10 = __builtin_amdgcn_mfma_f32_16x16x32_bf16(aQ1.v, k0, zero, 0, 0, 0);
        f32x4 s11 = __builtin_amdgcn_mfma_f32_16x16x32_bf16(aQ1.v, k1, zero, 0, 0, 0);

        // V frags for this chunk (early issue; used after the exp block)
        bf16x8 v0 = vf[(size_t)c * 128];
        bf16x8 v1 = vf[(size_t)c * 128 + 64];
        // prefetch K frags for next chunk (wrap: harmless reload)
        const int cn = (c + 1) & (NCH - 1);
        k0 = kf[(size_t)cn * 128];
        k1 = kf[(size_t)cn * 128 + 64];

        // exp + pack + P write (tile0 rows 0..15, tile1 rows 16..31)
        #pragma unroll
        for (int r = 0; r < 4; ++r) {
            float e0  = __builtin_amdgcn_exp2f(s00[r]);
            float en0 = __builtin_amdgcn_exp2f(-s00[r]);
            float e1  = __builtin_amdgcn_exp2f(s01[r]);
            float en1 = __builtin_amdgcn_exp2f(-s01[r]);
            den0[r] += (e0 + en0) + (e1 + en1);
            pbw[(quad * 4 + r) * (PROW / 2) + l16] = pk2(e0 - en0, e1 - en1);
        }
        #pragma unroll
        for (int r = 0; r < 4; ++r) {
            float e0  = __builtin_amdgcn_exp2f(s10[r]);
            float en0 = __builtin_amdgcn_exp2f(-s10[r]);
            float e1  = __builtin_amdgcn_exp2f(s11[r]);
            float en1 = __builtin_amdgcn_exp2f(-s11[r]);
            den1[r] += (e0 + en0) + (e1 + en1);
            pbw[(16 + quad * 4 + r) * (PROW / 2) + l16] = pk2(e0 - en0, e1 - en1);
        }

        // P: C-layout -> A-layout (same-wave LDS is in-order: RAW safe)
        bf16x8 aP0 = *(const bf16x8*)(pb + l16 * PROW + quad * 8);
        bf16x8 aP1 = *(const bf16x8*)(pb + (16 + l16) * PROW + quad * 8);

        o00 = __builtin_amdgcn_mfma_f32_16x16x32_bf16(aP0, v0, o00, 0, 0, 0);
        o01 = __builtin_amdgcn_mfma_f32_16x16x32_bf16(aP0, v1, o01, 0, 0, 0);
        o10 = __builtin_amdgcn_mfma_f32_16x16x32_bf16(aP1, v0, o10, 0, 0, 0);
        o11 = __builtin_amdgcn_mfma_f32_16x16x32_bf16(aP1, v1, o11, 0, 0, 0);
    }

    // den: reduce across the 16 key-column lanes of each quad group
    #pragma unroll
    for (int r = 0; r < 4; ++r) {
        den0[r] += __shfl_xor(den0[r], 1, 16);
        den0[r] += __shfl_xor(den0[r], 2, 16);
        den0[r] += __shfl_xor(den0[r], 4, 16);
        den0[r] += __shfl_xor(den0[r], 8, 16);
        den1[r] += __shfl_xor(den1[r], 1, 16);
        den1[r] += __shfl_xor(den1[r], 2, 16);
        den1[r] += __shfl_xor(den1[r], 4, 16);
        den1[r] += __shfl_xor(den1[r], 8, 16);
    }

    // cross-wave (key-half) combine
    if (kh == 1) {
        float* r = &Red[qi][lane][0];
        *(f32x4*)(r +  0) = o00; *(f32x4*)(r +  4) = o01;
        *(f32x4*)(r +  8) = o10; *(f32x4*)(r + 12) = o11;
        *(f32x4*)(r + 16) = den0; *(f32x4*)(r + 20) = den1;
    }
    __syncthreads();
    if (kh == 0) {
        const float* r = &Red[qi][lane][0];
        o00 += *(const f32x4*)(r +  0); o01 += *(const f32x4*)(r +  4);
        o10 += *(const f32x4*)(r +  8); o11 += *(const f32x4*)(r + 12);
        den0 += *(const f32x4*)(r + 16); den1 += *(const f32x4*)(r + 20);

        float* outp = Out + ((size_t)bh * SLEN + qbase) * DK;
        #pragma unroll
        for (int rr = 0; rr < 4; ++rr) {
            float inv0 = 1.0f / den0[rr];
            float inv1 = 1.0f / den1[rr];
            int q0 = quad * 4 + rr;
            int q1 = 16 + quad * 4 + rr;
            outp[(size_t)q0 * DK + l16]      = o00[rr] * inv0;
            outp[(size_t)q0 * DK + 16 + l16] = o01[rr] * inv0;
            outp[(size_t)q1 * DK + l16]      = o10[rr] * inv1;
            outp[(size_t)q1 * DK + 16 + l16] = o11[rr] * inv1;
        }
    }
}

extern "C" void kernel_launch(void* const* d_in, const int* in_sizes, int n_in,
                              void* d_out, int out_size, void* d_ws, size_t ws_size,
                              hipStream_t stream) {
    const float* Q = (const float*)d_in[0];
    const float* K = (const float*)d_in[1];
    const float* V = (const float*)d_in[2];
    // d_in[3] = attn_mask: no-op in reference, never read
    float* Out = (float*)d_out;
    unsigned short* Kbf = (unsigned short*)d_ws;                      // 6.29 MB
    unsigned short* VTf = Kbf + (size_t)NBH * SLEN * DK;              // 6.29 MB

    prep_kv<<<dim3(NBH * 32 + NBH * 64), dim3(256), 0, stream>>>(K, V, Kbf, VTf);
    attn_mfma<<<dim3(1536), dim3(256), 0, stream>>>(Q, Kbf, VTf, Out);
}

// Round 6
// 926.620 us; speedup vs baseline: 1.0003x; 1.0003x over previous
//
#include <hip/hip_runtime.h>
#include <hip/hip_bf16.h>
#include <cstdint>
#include <cstddef>

// tanh_max attention, B=4 H=12 S=2048 D=32, fp32 in/out. attn_mask is a
// faithful no-op in the reference -> never read.
//
// R6: TRANSPOSED-SCORE design -- P never leaves registers.
//   R3==R4==R5 (~163us) with all throughput pipes modeled <=23us => the
//   common serial spine is the limiter: the P C-layout->A-layout LDS round
//   trip (8 ds_write + lgkmcnt(0) + ds_read, ~120-240cyc) on every chunk's
//   critical path. Fix: compute S^T = MFMA(A=K, B=Q) (A/B frags are mirror
//   layouts for 16x16). With K prep permutation key = 8*floor(m/4)+2*(m%4)+t,
//   the packed pk2(w_t0[r], w_t1[r]) IS the PV A-frag register r directly:
//   keys (8*quad+2r, 8*quad+2r+1). Zero LDS ops in the hot loop.
//   - den becomes one scalar per lane (q=l16): 2 shuffles, fewer VALU adds.
//   - everything else (grid 1536, 32q/wave, 2 key halves, XCD clustering,
//     K prefetch) identical to R5 for clean attribution.

#define SLEN 2048
#define DK   32
#define NBH  48
#define NCH  32   // 32-key chunks per wave (1024 keys)

typedef __attribute__((ext_vector_type(8))) short bf16x8;
typedef __attribute__((ext_vector_type(4))) float f32x4;

__device__ __forceinline__ unsigned pk2(float a, float b) {
    __hip_bfloat162 h = __float22bfloat162_rn(make_float2(a, b));
    union { __hip_bfloat162 h2; unsigned u; } cv; cv.h2 = h; return cv.u;
}

// ---- fused prep ------------------------------------------------------------
// Kbf: A-frag order for tile T=2c+t of chunk c:
//   frag ((bh*128+T)*64 + l) elem j = K[bh][key][(l>>4)*8+j],
//   key = c*32 + 8*((l&15)>>2) + 2*((l&15)&3) + t
//   (so C-layout row m=quad*4+r of tile t is actual key 8*quad+2r+t).
// VTf: B-frag order (V^T), natural key order within chunk:
//   frag (((bh*64+c)*2+h)*64 + l) elem j = V[bh][c*32+(l>>4)*8+j][h*16+(l&15)]
__global__ __launch_bounds__(256)
void prep_kv(const float* __restrict__ K, const float* __restrict__ V,
             unsigned short* __restrict__ Kbf, unsigned short* __restrict__ VTf) {
    if (blockIdx.x < NBH * 32) {
        const int b  = blockIdx.x;
        const int bh = b >> 5, kg = b & 31;
        const int tl = threadIdx.x >> 6, l = threadIdx.x & 63;
        const int T  = kg * 4 + tl;
        const int c  = T >> 1, tb = T & 1;
        const int l16 = l & 15;
        const int key = c * 32 + 8 * (l16 >> 2) + 2 * (l16 & 3) + tb;
        const float* src = K + ((size_t)bh * SLEN + key) * DK + (l >> 4) * 8;
        float4 a = *(const float4*)src;
        float4 b4 = *(const float4*)(src + 4);
        union { uint4 q; unsigned u[4]; } o;
        o.u[0] = pk2(a.x, a.y);  o.u[1] = pk2(a.z, a.w);
        o.u[2] = pk2(b4.x, b4.y); o.u[3] = pk2(b4.z, b4.w);
        *(uint4*)(Kbf + (((size_t)bh * 128 + T) * 64 + l) * 8) = o.q;
    } else {
        __shared__ float tile[32][33];
        const int b  = blockIdx.x - NBH * 32;
        const int bh = b >> 6, c = b & 63;
        const int t  = threadIdx.x;
        {
            const int row = t >> 3, c4 = (t & 7) * 4;
            float4 v4 = *(const float4*)(V + ((size_t)bh * SLEN + c * 32 + row) * DK + c4);
            tile[row][c4 + 0] = v4.x; tile[row][c4 + 1] = v4.y;
            tile[row][c4 + 2] = v4.z; tile[row][c4 + 3] = v4.w;
        }
        __syncthreads();
        const int h = t >> 7, l = (t >> 1) & 63, jh = t & 1;
        const int col = h * 16 + (l & 15);
        const int r0  = (l >> 4) * 8 + jh * 4;
        uint2 u;
        u.x = pk2(tile[r0 + 0][col], tile[r0 + 1][col]);
        u.y = pk2(tile[r0 + 2][col], tile[r0 + 3][col]);
        *(uint2*)(VTf + ((((size_t)bh * 64 + c) * 2 + h) * 64 + l) * 8 + jh * 4) = u;
    }
}

// ---- main: MFMA attention, transposed scores, LDS-free hot loop ------------
__global__ __launch_bounds__(256, 4)
void attn_mfma(const float* __restrict__ Q, const unsigned short* __restrict__ Kbf,
               const unsigned short* __restrict__ VTf, float* __restrict__ Out) {
    __shared__ __align__(16) float Red[2][64][20];   // 10240 B (cross-wave combine)

    const int tid  = threadIdx.x;
    const int lane = tid & 63;
    const int wv   = tid >> 6;
    const int quad = lane >> 4;
    const int l16  = lane & 15;
    const int qi   = wv >> 1;          // q-group within block
    const int kh   = wv & 1;           // key half

    // XCD-aware head clustering: 6 heads per XCD.
    const int b   = blockIdx.x;        // grid = 1536
    const int xcd = b & 7;
    const int i   = b >> 3;            // 0..191
    const int bh  = xcd * 6 + (i % 6);
    const int j   = i / 6;             // 0..31
    const int qbase = (j * 2 + qi) * 32;

    // Q frags (used as B operand; B layout mirrors A for 16x16: lane holds
    // column n=l16, elems k=quad*8+j). Scaled by (1/sqrt(32))*log2(e).
    const float sc = 0.17677669529663687f * 1.4426950408889634f;
    union { bf16x8 v; unsigned u[4]; } aQ0, aQ1;
    {
        const float* qp0 = Q + ((size_t)bh * SLEN + qbase + l16) * DK + quad * 8;
        float4 qa = *(const float4*)qp0;
        float4 qb = *(const float4*)(qp0 + 4);
        aQ0.u[0] = pk2(qa.x * sc, qa.y * sc); aQ0.u[1] = pk2(qa.z * sc, qa.w * sc);
        aQ0.u[2] = pk2(qb.x * sc, qb.y * sc); aQ0.u[3] = pk2(qb.z * sc, qb.w * sc);
        const float* qp1 = qp0 + 16 * DK;
        float4 qc = *(const float4*)qp1;
        float4 qd = *(const float4*)(qp1 + 4);
        aQ1.u[0] = pk2(qc.x * sc, qc.y * sc); aQ1.u[1] = pk2(qc.z * sc, qc.w * sc);
        aQ1.u[2] = pk2(qd.x * sc, qd.y * sc); aQ1.u[3] = pk2(qd.z * sc, qd.w * sc);
    }

    // frag streams for this wave's key half (chunk c: tiles at c*128 + {0,64})
    const bf16x8* kf = (const bf16x8*)Kbf + ((size_t)bh * 128 + kh * 64) * 64 + lane;
    const bf16x8* vf = (const bf16x8*)VTf + ((size_t)bh * 128 + kh * 64) * 64 + lane;

    f32x4 o00 = {0,0,0,0}, o01 = {0,0,0,0};   // q-tile0: O[q=quad*4+r][d=l16 / 16+l16]
    f32x4 o10 = {0,0,0,0}, o11 = {0,0,0,0};   // q-tile1
    float den0 = 0.f, den1 = 0.f;             // per-lane: q = l16 (+16)
    const f32x4 zero = {0,0,0,0};

    bf16x8 k0 = kf[0], k1 = kf[64];

    for (int c = 0; c < NCH; ++c) {
        // S^T tiles: A=K (rows=keys), B=Q (cols=queries)
        f32x4 s00 = __builtin_amdgcn_mfma_f32_16x16x32_bf16(k0, aQ0.v, zero, 0, 0, 0);
        f32x4 s01 = __builtin_amdgcn_mfma_f32_16x16x32_bf16(k1, aQ0.v, zero, 0, 0, 0);
        f32x4 s10 = __builtin_amdgcn_mfma_f32_16x16x32_bf16(k0, aQ1.v, zero, 0, 0, 0);
        f32x4 s11 = __builtin_amdgcn_mfma_f32_16x16x32_bf16(k1, aQ1.v, zero, 0, 0, 0);

        // V frags for this chunk (early issue; used after exp block)
        bf16x8 v0 = vf[(size_t)c * 128];
        bf16x8 v1 = vf[(size_t)c * 128 + 64];
        // prefetch K frags for next chunk (wrap: harmless reload)
        const int cn = (c + 1) & (NCH - 1);
        k0 = kf[(size_t)cn * 128];
        k1 = kf[(size_t)cn * 128 + 64];

        // exp + pack: aP reg r = keys (8*quad+2r, 8*quad+2r+1) -> PV A-frag
        union { bf16x8 v; unsigned u[4]; } aP0, aP1;
        #pragma unroll
        for (int r = 0; r < 4; ++r) {
            float e0  = __builtin_amdgcn_exp2f(s00[r]);
            float en0 = __builtin_amdgcn_exp2f(-s00[r]);
            float e1  = __builtin_amdgcn_exp2f(s01[r]);
            float en1 = __builtin_amdgcn_exp2f(-s01[r]);
            den0 += (e0 + en0) + (e1 + en1);
            aP0.u[r] = pk2(e0 - en0, e1 - en1);
        }
        #pragma unroll
        for (int r = 0; r < 4; ++r) {
            float e0  = __builtin_amdgcn_exp2f(s10[r]);
            float en0 = __builtin_amdgcn_exp2f(-s10[r]);
            float e1  = __builtin_amdgcn_exp2f(s11[r]);
            float en1 = __builtin_amdgcn_exp2f(-s11[r]);
            den1 += (e0 + en0) + (e1 + en1);
            aP1.u[r] = pk2(e0 - en0, e1 - en1);
        }

        // PV: A=P (rows=queries), B=V^T -> O[q=quad*4+r][d=l16 / 16+l16]
        o00 = __builtin_amdgcn_mfma_f32_16x16x32_bf16(aP0.v, v0, o00, 0, 0, 0);
        o01 = __builtin_amdgcn_mfma_f32_16x16x32_bf16(aP0.v, v1, o01, 0, 0, 0);
        o10 = __builtin_amdgcn_mfma_f32_16x16x32_bf16(aP1.v, v0, o10, 0, 0, 0);
        o11 = __builtin_amdgcn_mfma_f32_16x16x32_bf16(aP1.v, v1, o11, 0, 0, 0);
    }

    // den: each lane covered keys {8*quad..8*quad+7} per chunk for q=l16;
    // combine quads: after xor16+xor32, every lane with index l16 (mod 16)
    // holds the full-wave den for query l16.
    den0 += __shfl_xor(den0, 16); den0 += __shfl_xor(den0, 32);
    den1 += __shfl_xor(den1, 16); den1 += __shfl_xor(den1, 32);

    // cross-wave (key-half) combine
    if (kh == 1) {
        float* r = &Red[qi][lane][0];
        *(f32x4*)(r +  0) = o00; *(f32x4*)(r +  4) = o01;
        *(f32x4*)(r +  8) = o10; *(f32x4*)(r + 12) = o11;
        r[16] = den0; r[17] = den1;
    }
    __syncthreads();
    if (kh == 0) {
        const float* r = &Red[qi][lane][0];
        o00 += *(const f32x4*)(r +  0); o01 += *(const f32x4*)(r +  4);
        o10 += *(const f32x4*)(r +  8); o11 += *(const f32x4*)(r + 12);
        den0 += r[16]; den1 += r[17];

        float* outp = Out + ((size_t)bh * SLEN + qbase) * DK;
        #pragma unroll
        for (int rr = 0; rr < 4; ++rr) {
            // den for row q=quad*4+rr lives at lane (segment | q): width-16 shfl
            float inv0 = 1.0f / __shfl(den0, quad * 4 + rr, 16);
            float inv1 = 1.0f / __shfl(den1, quad * 4 + rr, 16);
            int q0 = quad * 4 + rr;
            int q1 = 16 + quad * 4 + rr;
            outp[(size_t)q0 * DK + l16]      = o00[rr] * inv0;
            outp[(size_t)q0 * DK + 16 + l16] = o01[rr] * inv0;
            outp[(size_t)q1 * DK + l16]      = o10[rr] * inv1;
            outp[(size_t)q1 * DK + 16 + l16] = o11[rr] * inv1;
        }
    }
}

extern "C" void kernel_launch(void* const* d_in, const int* in_sizes, int n_in,
                              void* d_out, int out_size, void* d_ws, size_t ws_size,
                              hipStream_t stream) {
    const float* Q = (const float*)d_in[0];
    const float* K = (const float*)d_in[1];
    const float* V = (const float*)d_in[2];
    // d_in[3] = attn_mask: no-op in reference, never read
    float* Out = (float*)d_out;
    unsigned short* Kbf = (unsigned short*)d_ws;                      // 6.29 MB
    unsigned short* VTf = Kbf + (size_t)NBH * SLEN * DK;              // 6.29 MB

    prep_kv<<<dim3(NBH * 32 + NBH * 64), dim3(256), 0, stream>>>(K, V, Kbf, VTf);
    attn_mfma<<<dim3(1536), dim3(256), 0, stream>>>(Q, Kbf, VTf, Out);
}